// Round 3
// baseline (570.504 us; speedup 1.0000x reference)
//
#include <hip/hip_runtime.h>

// SNN forward. Round 3: the round-2 counters showed device-scope atomicAdd
// write-through (31 B fabric write per atomic, WRITE_SIZE unchanged by
// privatization). Fix: per-XCD accumulator copies selected by the HW XCC_ID
// register + workgroup-scope relaxed atomics, which execute in the local
// XCD's L2 (no coherence-point bypass). Kernel-boundary release/acquire
// writes the dirty L2 lines back before the reduce kernel reads them.

#define N_SENS 10000
#define N_HID  400000
#define N_MOT  1000
#define NB_HM  256
#define N_XCD  8

__device__ __forceinline__ int xcd_id() {
    int x;
    asm("s_getreg_b32 %0, hwreg(HW_REG_XCC_ID, 0, 32)" : "=s"(x));
    return x & (N_XCD - 1);
}

__global__ void lif_kernel(const float* __restrict__ inp,
                           const float* __restrict__ mem_in,
                           float* __restrict__ spk,
                           float scale, int n) {
    int i = blockIdx.x * blockDim.x + threadIdx.x;
    if (i < n) {
        float m = 0.9f * mem_in[i] + scale * inp[i];
        spk[i] = (m > 1.0f) ? 1.0f : 0.0f;
    }
}

// Fast path: copies[xcd][post[e]] += scale*w[e]*spike. Each copy is touched
// by exactly ONE XCD (hardware XCC_ID, not blockIdx heuristics), so
// workgroup-scope atomics performed in that XCD's L2 are fully atomic for
// the copy and stay cached (no per-atomic fabric write-through).
__global__ void scatter_xcd(const int* __restrict__ pre,
                            const int* __restrict__ post,
                            const float* __restrict__ w,
                            const float* __restrict__ spikes,
                            float* __restrict__ copies,
                            float scale, int n_edges) {
    int e = blockIdx.x * blockDim.x + threadIdx.x;
    if (e >= n_edges) return;
    float s = spikes[pre[e]];
    if (s != 0.0f) {
        float* dst = copies + (size_t)xcd_id() * N_HID;
        __hip_atomic_fetch_add(&dst[post[e]], scale * w[e] * s,
                               __ATOMIC_RELAXED, __HIP_MEMORY_SCOPE_WORKGROUP);
    }
}

// Fallback if workspace can't hold 8 copies: device-scope atomics, 1 copy.
__global__ void scatter_dev(const int* __restrict__ pre,
                            const int* __restrict__ post,
                            const float* __restrict__ w,
                            const float* __restrict__ spikes,
                            float* __restrict__ out,
                            float scale, int n_edges) {
    int e = blockIdx.x * blockDim.x + threadIdx.x;
    if (e >= n_edges) return;
    float s = spikes[pre[e]];
    if (s != 0.0f) atomicAdd(&out[post[e]], scale * w[e] * s);
}

// hid_spk[i] = LIF( sum_c copies[c][i] ), float4-vectorized
__global__ void reduce_lif_hidden(const float* __restrict__ copies, int n_copies,
                                  const float* __restrict__ mem,
                                  float* __restrict__ spk) {
    int i4 = blockIdx.x * blockDim.x + threadIdx.x;   // quad index
    if (i4 >= N_HID / 4) return;
    float4 sum = make_float4(0.f, 0.f, 0.f, 0.f);
    for (int c = 0; c < n_copies; ++c) {
        float4 v = ((const float4*)(copies + (size_t)c * N_HID))[i4];
        sum.x += v.x; sum.y += v.y; sum.z += v.z; sum.w += v.w;
    }
    float4 mm = ((const float4*)mem)[i4];
    float4 o;
    o.x = (0.9f * mm.x + 5.0f * sum.x > 1.0f) ? 1.0f : 0.0f;
    o.y = (0.9f * mm.y + 5.0f * sum.y > 1.0f) ? 1.0f : 0.0f;
    o.z = (0.9f * mm.z + 5.0f * sum.z > 1.0f) ? 1.0f : 0.0f;
    o.w = (0.9f * mm.w + 5.0f * sum.w > 1.0f) ? 1.0f : 0.0f;
    ((float4*)spk)[i4] = o;
}

// Motor: per-block LDS accumulator, per-block partials, no global atomics.
__global__ void scatter_motor(const int* __restrict__ pre,
                              const int* __restrict__ post,
                              const float* __restrict__ w,
                              const float* __restrict__ spikes,
                              float* __restrict__ partials, int n_edges) {
    __shared__ float acc[N_MOT];
    for (int j = threadIdx.x; j < N_MOT; j += blockDim.x) acc[j] = 0.0f;
    __syncthreads();
    for (int e = blockIdx.x * blockDim.x + threadIdx.x; e < n_edges;
         e += gridDim.x * blockDim.x) {
        float s = spikes[pre[e]];
        if (s != 0.0f) atomicAdd(&acc[post[e]], w[e] * s);
    }
    __syncthreads();
    float* out = partials + (size_t)blockIdx.x * N_MOT;
    for (int j = threadIdx.x; j < N_MOT; j += blockDim.x) out[j] = acc[j];
}

__global__ void reduce_lif_motor(const float* __restrict__ partials, int nb,
                                 const float* __restrict__ mem,
                                 float* __restrict__ out) {
    int m = blockIdx.x * blockDim.x + threadIdx.x;
    if (m >= N_MOT) return;
    float sum = 0.0f;
    for (int b = 0; b < nb; ++b) sum += partials[(size_t)b * N_MOT + m];
    float v = 0.9f * mem[m] + 20.0f * sum;
    out[m] = (v > 1.0f) ? 1.0f : 0.0f;
}

extern "C" void kernel_launch(void* const* d_in, const int* in_sizes, int n_in,
                              void* d_out, int out_size, void* d_ws, size_t ws_size,
                              hipStream_t stream) {
    const float* sensory_input = (const float*)d_in[0];
    const float* sensory_mem   = (const float*)d_in[1];
    const float* hidden_mem    = (const float*)d_in[2];
    const float* motor_mem     = (const float*)d_in[3];
    const float* hidden_prev   = (const float*)d_in[4];
    const float* w_sh          = (const float*)d_in[5];
    const float* w_hh          = (const float*)d_in[6];
    const float* w_hm          = (const float*)d_in[7];
    const int*   sh_pre        = (const int*)d_in[8];
    const int*   sh_post       = (const int*)d_in[9];
    const int*   hh_pre        = (const int*)d_in[10];
    const int*   hh_post       = (const int*)d_in[11];
    const int*   hm_pre        = (const int*)d_in[12];
    const int*   hm_post       = (const int*)d_in[13];
    const int e_sh = in_sizes[5];
    const int e_hh = in_sizes[6];
    const int e_hm = in_sizes[7];

    // ws layout (floats): [copies n_copies*400K][partials NB_HM*1000]
    //                     [sens_spk 10K][hid_spk 400K]
    size_t floats_avail = ws_size / sizeof(float);
    size_t fixed = (size_t)N_SENS + N_HID + (size_t)NB_HM * N_MOT;
    long avail_for_copies = (long)floats_avail - (long)fixed;
    int n_copies = (int)(avail_for_copies / N_HID);
    bool fast = (n_copies >= N_XCD);
    n_copies = fast ? N_XCD : 1;

    float* ws       = (float*)d_ws;
    float* copies   = ws;
    float* partials = copies + (size_t)n_copies * N_HID;
    float* sens_spk = partials + (size_t)NB_HM * N_MOT;
    float* hid_spk  = sens_spk + N_SENS;

    hipMemsetAsync(copies, 0,
                   ((size_t)n_copies * N_HID + (size_t)NB_HM * N_MOT) * sizeof(float),
                   stream);

    const int B = 256;
    lif_kernel<<<(N_SENS + B - 1) / B, B, 0, stream>>>(sensory_input, sensory_mem,
                                                       sens_spk, 5.0f, N_SENS);
    if (fast) {
        scatter_xcd<<<(e_sh + B - 1) / B, B, 0, stream>>>(sh_pre, sh_post, w_sh,
                                                          sens_spk, copies, 1.0f, e_sh);
        scatter_xcd<<<(e_hh + B - 1) / B, B, 0, stream>>>(hh_pre, hh_post, w_hh,
                                                          hidden_prev, copies, 0.5f, e_hh);
    } else {
        scatter_dev<<<(e_sh + B - 1) / B, B, 0, stream>>>(sh_pre, sh_post, w_sh,
                                                          sens_spk, copies, 1.0f, e_sh);
        scatter_dev<<<(e_hh + B - 1) / B, B, 0, stream>>>(hh_pre, hh_post, w_hh,
                                                          hidden_prev, copies, 0.5f, e_hh);
    }
    reduce_lif_hidden<<<(N_HID / 4 + B - 1) / B, B, 0, stream>>>(copies, n_copies,
                                                                 hidden_mem, hid_spk);
    scatter_motor<<<NB_HM, B, 0, stream>>>(hm_pre, hm_post, w_hm,
                                           hid_spk, partials, e_hm);
    reduce_lif_motor<<<(N_MOT + B - 1) / B, B, 0, stream>>>(partials, NB_HM,
                                                            motor_mem, (float*)d_out);
}

// Round 4
// 512.096 us; speedup vs baseline: 1.1141x; 1.1141x over previous
//
#include <hip/hip_runtime.h>

// SNN forward, round 4: global fp atomics are the measured bottleneck
// (~31 B fabric write-through + ~20 atomics/ns ceiling, invariant under
// address privatization AND scope lowering -> structural fix only).
// Replace scatter-atomics with: bin active edges by 16K-neuron post-chunk
// (plain stores, LDS histogram ranks), then per-chunk LDS ds_add_f32
// accumulation, then partial-merge fused into the hidden LIF.

#define N_SENS 10000
#define N_HID  400000
#define N_MOT  1000
#define NB_HM  256

#define CHUNK_LOG 14
#define CHUNK     (1 << CHUNK_LOG)      // 16384 floats = 64 KB LDS
#define NBUCKET   25                    // ceil(400000 / 16384)
#define CAP       (1 << 18)             // 262144 pairs/bucket (need ~175K)
#define NCOPY     12                    // accumulation copies per bucket
#define EPT       8                     // edges per thread in binning

__global__ void lif_kernel(const float* __restrict__ inp,
                           const float* __restrict__ mem_in,
                           float* __restrict__ spk,
                           float scale, int n) {
    int i = blockIdx.x * blockDim.x + threadIdx.x;
    if (i < n) {
        float m = 0.9f * mem_in[i] + scale * inp[i];
        spk[i] = (m > 1.0f) ? 1.0f : 0.0f;
    }
}

// Phase A: compact+bin active edges. pairs[bucket*CAP + slot] = (local, val).
// Slots via LDS histogram (rank) + one global cursor atomic per bucket/block.
__global__ void bin_edges(const int* __restrict__ pre,
                          const int* __restrict__ post,
                          const float* __restrict__ w,
                          const float* __restrict__ spikes,
                          float scale,
                          uint2* __restrict__ pairs,
                          int* __restrict__ cursors,
                          int n_edges) {
    __shared__ int h[NBUCKET];
    __shared__ int base[NBUCKET];
    if (threadIdx.x < NBUCKET) h[threadIdx.x] = 0;
    __syncthreads();

    int blockStart = blockIdx.x * (blockDim.x * EPT);
    int  bkt[EPT];
    int  rnk[EPT];
    uint2 pv[EPT];
    #pragma unroll
    for (int j = 0; j < EPT; ++j) {
        bkt[j] = -1;
        int e = blockStart + j * blockDim.x + threadIdx.x;   // coalesced
        if (e < n_edges) {
            float s = spikes[pre[e]];
            if (s != 0.0f) {                                  // s is exactly 1.0
                int p = post[e];
                int b = p >> CHUNK_LOG;
                bkt[j] = b;
                pv[j]  = make_uint2((unsigned)(p & (CHUNK - 1)),
                                    __float_as_uint(scale * w[e]));
                rnk[j] = atomicAdd(&h[b], 1);                 // LDS atomic
            }
        }
    }
    __syncthreads();
    if (threadIdx.x < NBUCKET)
        base[threadIdx.x] = atomicAdd(&cursors[threadIdx.x], h[threadIdx.x]);
    __syncthreads();
    #pragma unroll
    for (int j = 0; j < EPT; ++j) {
        if (bkt[j] >= 0) {
            int slot = base[bkt[j]] + rnk[j];
            if (slot < CAP)                                   // safety clamp
                pairs[(size_t)bkt[j] * CAP + slot] = pv[j];
        }
    }
}

// Phase B: block (bucket,copy) accumulates its slice of the bucket's pairs
// into a 64 KB LDS chunk with ds_add_f32, then writes the partial chunk.
__global__ void accum_bucket(const uint2* __restrict__ pairs,
                             const int* __restrict__ cursors,
                             float* __restrict__ partials) {
    int bucket = blockIdx.x / NCOPY;
    int copy   = blockIdx.x % NCOPY;
    __shared__ float acc[CHUNK];
    for (int i = threadIdx.x; i < CHUNK; i += blockDim.x) acc[i] = 0.0f;
    __syncthreads();

    int count = cursors[bucket];
    if (count > CAP) count = CAP;
    int begin = (int)((long long)count * copy / NCOPY);
    int end   = (int)((long long)count * (copy + 1) / NCOPY);
    const uint2* src = pairs + (size_t)bucket * CAP;
    for (int i = begin + threadIdx.x; i < end; i += blockDim.x) {
        uint2 u = src[i];
        atomicAdd(&acc[u.x], __uint_as_float(u.y));           // LDS atomic
    }
    __syncthreads();
    float* dst = partials + ((size_t)bucket * NCOPY + copy) * CHUNK;
    for (int i = threadIdx.x; i < CHUNK; i += blockDim.x) dst[i] = acc[i];
}

// hid_spk[i] = LIF( sum_c partials[bucket(i)][c][local(i)] )
__global__ void reduce_lif_hidden(const float* __restrict__ partials,
                                  const float* __restrict__ mem,
                                  float* __restrict__ spk) {
    int i = blockIdx.x * blockDim.x + threadIdx.x;
    if (i >= N_HID) return;
    int b = i >> CHUNK_LOG, local = i & (CHUNK - 1);
    const float* p = partials + (size_t)b * NCOPY * CHUNK + local;
    float sum = 0.0f;
    #pragma unroll
    for (int c = 0; c < NCOPY; ++c) sum += p[(size_t)c * CHUNK];
    float m = 0.9f * mem[i] + 5.0f * sum;
    spk[i] = (m > 1.0f) ? 1.0f : 0.0f;
}

// Motor: per-block LDS accumulator + partials (no global atomics).
__global__ void scatter_motor(const int* __restrict__ pre,
                              const int* __restrict__ post,
                              const float* __restrict__ w,
                              const float* __restrict__ spikes,
                              float* __restrict__ partials, int n_edges) {
    __shared__ float acc[N_MOT];
    for (int j = threadIdx.x; j < N_MOT; j += blockDim.x) acc[j] = 0.0f;
    __syncthreads();
    for (int e = blockIdx.x * blockDim.x + threadIdx.x; e < n_edges;
         e += gridDim.x * blockDim.x) {
        float s = spikes[pre[e]];
        if (s != 0.0f) atomicAdd(&acc[post[e]], w[e] * s);
    }
    __syncthreads();
    float* out = partials + (size_t)blockIdx.x * N_MOT;
    for (int j = threadIdx.x; j < N_MOT; j += blockDim.x) out[j] = acc[j];
}

__global__ void reduce_lif_motor(const float* __restrict__ partials, int nb,
                                 const float* __restrict__ mem,
                                 float* __restrict__ out) {
    int m = blockIdx.x * blockDim.x + threadIdx.x;
    if (m >= N_MOT) return;
    float sum = 0.0f;
    for (int b = 0; b < nb; ++b) sum += partials[(size_t)b * N_MOT + m];
    float v = 0.9f * mem[m] + 20.0f * sum;
    out[m] = (v > 1.0f) ? 1.0f : 0.0f;
}

// Fallback (tiny workspace): plain device-atomic scatter.
__global__ void scatter_dev(const int* __restrict__ pre,
                            const int* __restrict__ post,
                            const float* __restrict__ w,
                            const float* __restrict__ spikes,
                            float* __restrict__ out,
                            float scale, int n_edges) {
    int e = blockIdx.x * blockDim.x + threadIdx.x;
    if (e >= n_edges) return;
    float s = spikes[pre[e]];
    if (s != 0.0f) atomicAdd(&out[post[e]], scale * w[e] * s);
}

__global__ void lif_hidden_direct(const float* __restrict__ hid_in,
                                  const float* __restrict__ mem,
                                  float* __restrict__ spk) {
    int i = blockIdx.x * blockDim.x + threadIdx.x;
    if (i >= N_HID) return;
    float m = 0.9f * mem[i] + 5.0f * hid_in[i];
    spk[i] = (m > 1.0f) ? 1.0f : 0.0f;
}

extern "C" void kernel_launch(void* const* d_in, const int* in_sizes, int n_in,
                              void* d_out, int out_size, void* d_ws, size_t ws_size,
                              hipStream_t stream) {
    const float* sensory_input = (const float*)d_in[0];
    const float* sensory_mem   = (const float*)d_in[1];
    const float* hidden_mem    = (const float*)d_in[2];
    const float* motor_mem     = (const float*)d_in[3];
    const float* hidden_prev   = (const float*)d_in[4];
    const float* w_sh          = (const float*)d_in[5];
    const float* w_hh          = (const float*)d_in[6];
    const float* w_hm          = (const float*)d_in[7];
    const int*   sh_pre        = (const int*)d_in[8];
    const int*   sh_post       = (const int*)d_in[9];
    const int*   hh_pre        = (const int*)d_in[10];
    const int*   hh_post       = (const int*)d_in[11];
    const int*   hm_pre        = (const int*)d_in[12];
    const int*   hm_post       = (const int*)d_in[13];
    const int e_sh = in_sizes[5];
    const int e_hh = in_sizes[6];
    const int e_hm = in_sizes[7];
    const int B = 256;

    // fast-path ws layout (floats):
    // [cursors 32][pairs NBUCKET*CAP*2][partials NBUCKET*NCOPY*CHUNK]
    // [sens_spk 10016][hid_spk 400000][mpart NB_HM*1000]
    size_t f_cursors  = 32;
    size_t f_pairs    = (size_t)NBUCKET * CAP * 2;
    size_t f_partials = (size_t)NBUCKET * NCOPY * CHUNK;
    size_t f_need = f_cursors + f_pairs + f_partials + 10016 + N_HID +
                    (size_t)NB_HM * N_MOT;
    bool fast = (ws_size / sizeof(float)) >= f_need;

    float* ws = (float*)d_ws;
    if (fast) {
        int*   cursors  = (int*)ws;
        uint2* pairs    = (uint2*)(ws + f_cursors);
        float* partials = ws + f_cursors + f_pairs;
        float* sens_spk = partials + f_partials;
        float* hid_spk  = sens_spk + 10016;
        float* mpart    = hid_spk + N_HID;

        hipMemsetAsync(cursors, 0, f_cursors * sizeof(float), stream);

        lif_kernel<<<(N_SENS + B - 1) / B, B, 0, stream>>>(
            sensory_input, sensory_mem, sens_spk, 5.0f, N_SENS);
        bin_edges<<<(e_sh + B * EPT - 1) / (B * EPT), B, 0, stream>>>(
            sh_pre, sh_post, w_sh, sens_spk, 1.0f, pairs, cursors, e_sh);
        bin_edges<<<(e_hh + B * EPT - 1) / (B * EPT), B, 0, stream>>>(
            hh_pre, hh_post, w_hh, hidden_prev, 0.5f, pairs, cursors, e_hh);
        accum_bucket<<<NBUCKET * NCOPY, 512, 0, stream>>>(pairs, cursors, partials);
        reduce_lif_hidden<<<(N_HID + B - 1) / B, B, 0, stream>>>(
            partials, hidden_mem, hid_spk);
        scatter_motor<<<NB_HM, B, 0, stream>>>(hm_pre, hm_post, w_hm,
                                               hid_spk, mpart, e_hm);
        reduce_lif_motor<<<(N_MOT + B - 1) / B, B, 0, stream>>>(
            mpart, NB_HM, motor_mem, (float*)d_out);
    } else {
        // fallback: single-copy device atomics
        float* hid_in   = ws;
        float* sens_spk = hid_in + N_HID;
        float* hid_spk  = sens_spk + 10016;
        float* mpart    = hid_spk + N_HID;
        hipMemsetAsync(hid_in, 0, (size_t)N_HID * sizeof(float), stream);
        lif_kernel<<<(N_SENS + B - 1) / B, B, 0, stream>>>(
            sensory_input, sensory_mem, sens_spk, 5.0f, N_SENS);
        scatter_dev<<<(e_sh + B - 1) / B, B, 0, stream>>>(
            sh_pre, sh_post, w_sh, sens_spk, hid_in, 1.0f, e_sh);
        scatter_dev<<<(e_hh + B - 1) / B, B, 0, stream>>>(
            hh_pre, hh_post, w_hh, hidden_prev, hid_in, 0.5f, e_hh);
        lif_hidden_direct<<<(N_HID + B - 1) / B, B, 0, stream>>>(
            hid_in, hidden_mem, hid_spk);
        scatter_motor<<<NB_HM, B, 0, stream>>>(hm_pre, hm_post, w_hm,
                                               hid_spk, mpart, e_hm);
        reduce_lif_motor<<<(N_MOT + B - 1) / B, B, 0, stream>>>(
            mpart, NB_HM, motor_mem, (float*)d_out);
    }
}

// Round 5
// 507.461 us; speedup vs baseline: 1.1242x; 1.0091x over previous
//
#include <hip/hip_runtime.h>

// SNN forward, round 5. Round-4 evidence: bin_edges(hh) = 172 us with all
// pipes idle (HBM 7%, VALU 6%) == divergent-gather bound (16M random 4B
// loads of spikes[pre[e]] serialize in TA/L1). Fix: spikes are 0/1 ->
// represent as bitmasks (400K bits = 50 KB) staged in LDS; the per-edge
// gather becomes an LDS bit test. Everything else (bin by 16K-post-chunk,
// LDS ds_add accumulate, fused reduce+LIF) stays from round 4.

#define N_SENS 10000
#define N_HID  400000
#define N_MOT  1000

#define CHUNK_LOG 14
#define CHUNK     (1 << CHUNK_LOG)      // 16384 floats = 64 KB LDS chunk
#define NBUCKET   25                    // ceil(400000 / 16384)
#define CAP       (1 << 18)             // pairs per bucket (need ~175K)
#define NCOPY     10                    // accum blocks per bucket (250 total)
#define NB_HM     128                   // motor scatter blocks

#define SENS_MW   320                   // sens mask words (uint32), 10048 bits
#define HID_MW    12512                 // hid mask words (uint32), 400384 bits

// --- mask builders: one uint64 ballot per wave ---------------------------
__global__ void make_mask_lif(const float* __restrict__ inp,
                              const float* __restrict__ mem,
                              float scale, uint2* __restrict__ mask,
                              int n, int nwords64) {
    int i = blockIdx.x * blockDim.x + threadIdx.x;
    bool pred = false;
    if (i < n) pred = (0.9f * mem[i] + scale * inp[i]) > 1.0f;
    unsigned long long b = __ballot(pred);
    if ((threadIdx.x & 63) == 0) {
        int w = i >> 6;
        if (w < nwords64)
            mask[w] = make_uint2((unsigned)b, (unsigned)(b >> 32));
    }
}

__global__ void make_mask_spk(const float* __restrict__ spk,
                              uint2* __restrict__ mask,
                              int n, int nwords64) {
    int i = blockIdx.x * blockDim.x + threadIdx.x;
    bool pred = false;
    if (i < n) pred = (spk[i] != 0.0f);
    unsigned long long b = __ballot(pred);
    if ((threadIdx.x & 63) == 0) {
        int w = i >> 6;
        if (w < nwords64)
            mask[w] = make_uint2((unsigned)b, (unsigned)(b >> 32));
    }
}

// --- Phase A: bin active edges, presyn test via LDS bitmask --------------
template<int MWORDS, int EPT>
__global__ void bin_edges_mask(const int* __restrict__ pre,
                               const int* __restrict__ post,
                               const float* __restrict__ w,
                               const unsigned* __restrict__ gmask,
                               float scale,
                               uint2* __restrict__ pairs,
                               int* __restrict__ cursors,
                               int n_edges) {
    __shared__ unsigned sm[MWORDS];
    __shared__ int h[NBUCKET];
    __shared__ int base[NBUCKET];
    for (int i = threadIdx.x; i < MWORDS; i += blockDim.x) sm[i] = gmask[i];
    if (threadIdx.x < NBUCKET) h[threadIdx.x] = 0;
    __syncthreads();

    int blockStart = blockIdx.x * (blockDim.x * EPT);
    int   bkt[EPT];
    int   rnk[EPT];
    uint2 pv[EPT];
    #pragma unroll
    for (int j = 0; j < EPT; ++j) {
        bkt[j] = -1;
        int e = blockStart + j * blockDim.x + threadIdx.x;   // coalesced
        if (e < n_edges) {
            int pr = pre[e];
            if ((sm[pr >> 5] >> (pr & 31)) & 1u) {           // LDS bit test
                int p = post[e];
                int b = p >> CHUNK_LOG;
                bkt[j] = b;
                pv[j]  = make_uint2((unsigned)(p & (CHUNK - 1)),
                                    __float_as_uint(scale * w[e]));
                rnk[j] = atomicAdd(&h[b], 1);                // LDS atomic
            }
        }
    }
    __syncthreads();
    if (threadIdx.x < NBUCKET)
        base[threadIdx.x] = atomicAdd(&cursors[threadIdx.x], h[threadIdx.x]);
    __syncthreads();
    #pragma unroll
    for (int j = 0; j < EPT; ++j) {
        if (bkt[j] >= 0) {
            int slot = base[bkt[j]] + rnk[j];
            if (slot < CAP)
                pairs[(size_t)bkt[j] * CAP + slot] = pv[j];
        }
    }
}

// --- Phase B: LDS ds_add accumulation per (bucket, copy) -----------------
__global__ void accum_bucket(const uint2* __restrict__ pairs,
                             const int* __restrict__ cursors,
                             float* __restrict__ partials) {
    int bucket = blockIdx.x / NCOPY;
    int copy   = blockIdx.x % NCOPY;
    __shared__ float acc[CHUNK];
    for (int i = threadIdx.x; i < CHUNK; i += blockDim.x) acc[i] = 0.0f;
    __syncthreads();

    int count = cursors[bucket];
    if (count > CAP) count = CAP;
    int begin = (int)((long long)count * copy / NCOPY);
    int end   = (int)((long long)count * (copy + 1) / NCOPY);
    const uint2* src = pairs + (size_t)bucket * CAP;
    for (int i = begin + threadIdx.x; i < end; i += blockDim.x) {
        uint2 u = src[i];
        atomicAdd(&acc[u.x], __uint_as_float(u.y));           // LDS atomic
    }
    __syncthreads();
    float* dst = partials + ((size_t)bucket * NCOPY + copy) * CHUNK;
    for (int i = threadIdx.x; i < CHUNK; i += blockDim.x) dst[i] = acc[i];
}

// --- hidden LIF fused with partial merge; emits spike BITMASK ------------
__global__ void reduce_lif_hidden_mask(const float* __restrict__ partials,
                                       const float* __restrict__ mem,
                                       uint2* __restrict__ mask) {
    int i = blockIdx.x * blockDim.x + threadIdx.x;
    bool pred = false;
    if (i < N_HID) {
        int b = i >> CHUNK_LOG, local = i & (CHUNK - 1);
        const float* p = partials + (size_t)b * NCOPY * CHUNK + local;
        float sum = 0.0f;
        #pragma unroll
        for (int c = 0; c < NCOPY; ++c) sum += p[(size_t)c * CHUNK];
        pred = (0.9f * mem[i] + 5.0f * sum) > 1.0f;
    }
    unsigned long long bal = __ballot(pred);
    if ((threadIdx.x & 63) == 0) {
        int w = i >> 6;
        if (w < HID_MW / 2)
            mask[w] = make_uint2((unsigned)bal, (unsigned)(bal >> 32));
    }
}

// --- motor: LDS accumulator + LDS hid bitmask, per-block partials --------
__global__ void scatter_motor_mask(const int* __restrict__ pre,
                                   const int* __restrict__ post,
                                   const float* __restrict__ w,
                                   const unsigned* __restrict__ gmask,
                                   float* __restrict__ partials, int n_edges) {
    __shared__ float acc[N_MOT];
    __shared__ unsigned sm[HID_MW];
    for (int i = threadIdx.x; i < HID_MW; i += blockDim.x) sm[i] = gmask[i];
    for (int j = threadIdx.x; j < N_MOT; j += blockDim.x) acc[j] = 0.0f;
    __syncthreads();
    for (int e = blockIdx.x * blockDim.x + threadIdx.x; e < n_edges;
         e += gridDim.x * blockDim.x) {
        int pr = pre[e];
        if ((sm[pr >> 5] >> (pr & 31)) & 1u)
            atomicAdd(&acc[post[e]], w[e]);
    }
    __syncthreads();
    float* out = partials + (size_t)blockIdx.x * N_MOT;
    for (int j = threadIdx.x; j < N_MOT; j += blockDim.x) out[j] = acc[j];
}

__global__ void reduce_lif_motor(const float* __restrict__ partials, int nb,
                                 const float* __restrict__ mem,
                                 float* __restrict__ out) {
    int m = blockIdx.x * blockDim.x + threadIdx.x;
    if (m >= N_MOT) return;
    float sum = 0.0f;
    for (int b = 0; b < nb; ++b) sum += partials[(size_t)b * N_MOT + m];
    float v = 0.9f * mem[m] + 20.0f * sum;
    out[m] = (v > 1.0f) ? 1.0f : 0.0f;
}

// --- fallback (tiny workspace): device-atomic scatter --------------------
__global__ void lif_kernel(const float* __restrict__ inp,
                           const float* __restrict__ mem_in,
                           float* __restrict__ spk,
                           float scale, int n) {
    int i = blockIdx.x * blockDim.x + threadIdx.x;
    if (i < n) {
        float m = 0.9f * mem_in[i] + scale * inp[i];
        spk[i] = (m > 1.0f) ? 1.0f : 0.0f;
    }
}

__global__ void scatter_dev(const int* __restrict__ pre,
                            const int* __restrict__ post,
                            const float* __restrict__ w,
                            const float* __restrict__ spikes,
                            float* __restrict__ out,
                            float scale, int n_edges) {
    int e = blockIdx.x * blockDim.x + threadIdx.x;
    if (e >= n_edges) return;
    float s = spikes[pre[e]];
    if (s != 0.0f) atomicAdd(&out[post[e]], scale * w[e] * s);
}

__global__ void lif_hidden_direct(const float* __restrict__ hid_in,
                                  const float* __restrict__ mem,
                                  float* __restrict__ spk) {
    int i = blockIdx.x * blockDim.x + threadIdx.x;
    if (i >= N_HID) return;
    float m = 0.9f * mem[i] + 5.0f * hid_in[i];
    spk[i] = (m > 1.0f) ? 1.0f : 0.0f;
}

__global__ void scatter_motor_f(const int* __restrict__ pre,
                                const int* __restrict__ post,
                                const float* __restrict__ w,
                                const float* __restrict__ spikes,
                                float* __restrict__ partials, int n_edges) {
    __shared__ float acc[N_MOT];
    for (int j = threadIdx.x; j < N_MOT; j += blockDim.x) acc[j] = 0.0f;
    __syncthreads();
    for (int e = blockIdx.x * blockDim.x + threadIdx.x; e < n_edges;
         e += gridDim.x * blockDim.x) {
        float s = spikes[pre[e]];
        if (s != 0.0f) atomicAdd(&acc[post[e]], w[e] * s);
    }
    __syncthreads();
    float* out = partials + (size_t)blockIdx.x * N_MOT;
    for (int j = threadIdx.x; j < N_MOT; j += blockDim.x) out[j] = acc[j];
}

extern "C" void kernel_launch(void* const* d_in, const int* in_sizes, int n_in,
                              void* d_out, int out_size, void* d_ws, size_t ws_size,
                              hipStream_t stream) {
    const float* sensory_input = (const float*)d_in[0];
    const float* sensory_mem   = (const float*)d_in[1];
    const float* hidden_mem    = (const float*)d_in[2];
    const float* motor_mem     = (const float*)d_in[3];
    const float* hidden_prev   = (const float*)d_in[4];
    const float* w_sh          = (const float*)d_in[5];
    const float* w_hh          = (const float*)d_in[6];
    const float* w_hm          = (const float*)d_in[7];
    const int*   sh_pre        = (const int*)d_in[8];
    const int*   sh_post       = (const int*)d_in[9];
    const int*   hh_pre        = (const int*)d_in[10];
    const int*   hh_post       = (const int*)d_in[11];
    const int*   hm_pre        = (const int*)d_in[12];
    const int*   hm_post       = (const int*)d_in[13];
    const int e_sh = in_sizes[5];
    const int e_hh = in_sizes[6];
    const int e_hm = in_sizes[7];
    const int B = 256;

    // fast ws layout (floats, all offsets even for uint2 alignment):
    size_t o_cursors = 0;                              // 32
    size_t o_pairs   = 32;                             // NBUCKET*CAP*2
    size_t o_part    = o_pairs + (size_t)NBUCKET * CAP * 2;     // NBUCKET*NCOPY*CHUNK
    size_t o_smask   = o_part + (size_t)NBUCKET * NCOPY * CHUNK; // SENS_MW
    size_t o_hmaskp  = o_smask + SENS_MW;              // HID_MW (prev spikes)
    size_t o_hmasks  = o_hmaskp + HID_MW;              // HID_MW (hid spikes)
    size_t o_mpart   = o_hmasks + HID_MW;              // NB_HM*N_MOT
    size_t f_need    = o_mpart + (size_t)NB_HM * N_MOT;
    bool fast = (ws_size / sizeof(float)) >= f_need;

    float* ws = (float*)d_ws;
    if (fast) {
        int*      cursors = (int*)(ws + o_cursors);
        uint2*    pairs   = (uint2*)(ws + o_pairs);
        float*    part    = ws + o_part;
        unsigned* smask   = (unsigned*)(ws + o_smask);
        unsigned* hmaskp  = (unsigned*)(ws + o_hmaskp);
        unsigned* hmasks  = (unsigned*)(ws + o_hmasks);
        float*    mpart   = ws + o_mpart;

        hipMemsetAsync(cursors, 0, 32 * sizeof(int), stream);

        make_mask_lif<<<(SENS_MW * 32 + B - 1) / B, B, 0, stream>>>(
            sensory_input, sensory_mem, 5.0f, (uint2*)smask, N_SENS, SENS_MW / 2);
        make_mask_spk<<<(N_HID + B - 1) / B, B, 0, stream>>>(
            hidden_prev, (uint2*)hmaskp, N_HID, HID_MW / 2);
        bin_edges_mask<SENS_MW, 8><<<(e_sh + B * 8 - 1) / (B * 8), B, 0, stream>>>(
            sh_pre, sh_post, w_sh, smask, 1.0f, pairs, cursors, e_sh);
        bin_edges_mask<HID_MW, 16><<<(e_hh + B * 16 - 1) / (B * 16), B, 0, stream>>>(
            hh_pre, hh_post, w_hh, hmaskp, 0.5f, pairs, cursors, e_hh);
        accum_bucket<<<NBUCKET * NCOPY, 512, 0, stream>>>(pairs, cursors, part);
        reduce_lif_hidden_mask<<<(N_HID + B - 1) / B, B, 0, stream>>>(
            part, hidden_mem, (uint2*)hmasks);
        scatter_motor_mask<<<NB_HM, B, 0, stream>>>(
            hm_pre, hm_post, w_hm, hmasks, mpart, e_hm);
        reduce_lif_motor<<<(N_MOT + B - 1) / B, B, 0, stream>>>(
            mpart, NB_HM, motor_mem, (float*)d_out);
    } else {
        float* hid_in   = ws;
        float* sens_spk = hid_in + N_HID;
        float* hid_spk  = sens_spk + 10016;
        float* mpart    = hid_spk + N_HID;
        hipMemsetAsync(hid_in, 0, (size_t)N_HID * sizeof(float), stream);
        lif_kernel<<<(N_SENS + B - 1) / B, B, 0, stream>>>(
            sensory_input, sensory_mem, sens_spk, 5.0f, N_SENS);
        scatter_dev<<<(e_sh + B - 1) / B, B, 0, stream>>>(
            sh_pre, sh_post, w_sh, sens_spk, hid_in, 1.0f, e_sh);
        scatter_dev<<<(e_hh + B - 1) / B, B, 0, stream>>>(
            hh_pre, hh_post, w_hh, hidden_prev, hid_in, 0.5f, e_hh);
        lif_hidden_direct<<<(N_HID + B - 1) / B, B, 0, stream>>>(
            hid_in, hidden_mem, hid_spk);
        scatter_motor_f<<<NB_HM, B, 0, stream>>>(
            hm_pre, hm_post, w_hm, hid_spk, mpart, e_hm);
        reduce_lif_motor<<<(N_MOT + B - 1) / B, B, 0, stream>>>(
            mpart, NB_HM, motor_mem, (float*)d_out);
    }
}

// Round 6
// 419.328 us; speedup vs baseline: 1.3605x; 1.2102x over previous
//
#include <hip/hip_runtime.h>

// SNN forward, round 6. Round-5 lesson: LDS bitmask test is fast per-wave
// but 50 KB LDS at B=256 crushed occupancy to 30% (latency-bound phase).
// Fix: 1024-thread bin blocks (2/CU, 100% occupancy), two-pass count/write
// binning (no per-thread arrays -> ~20 VGPR, launch_bounds(1024,8)),
// sh+hh merged into one dispatch, accum at NCOPY=20/B=1024 (was 25%-occ,
// grid-starved at 250 blocks).

#define N_SENS 10000
#define N_HID  400000
#define N_MOT  1000

#define CHUNK_LOG 14
#define CHUNK     (1 << CHUNK_LOG)      // 16384 floats = 64 KB LDS chunk
#define NBUCKET   25                    // ceil(400000 / 16384)
#define CAP       204800                // pairs/bucket (expect ~179K)
#define NCOPY     20                    // accum blocks per bucket (500 total)
#define NB_HM     128

#define SENS_MW   320                   // sens mask words (u32) = 10240 bits
#define HID_MW    12512                 // hid mask words (u32) = 400384 bits

#define BIN_B     1024
#define BIN_EPT   16                    // edges per thread per pass

// --- masks for sensory (LIF on the fly) and hidden_prev (0/1 floats) -----
__global__ void make_masks(const float* __restrict__ sens_in,
                           const float* __restrict__ sens_mem,
                           const float* __restrict__ hid_prev,
                           uint2* __restrict__ smask,
                           uint2* __restrict__ hmask, int nb_sens) {
    bool pred = false;
    int i;
    uint2* dst;
    int maxw;
    if ((int)blockIdx.x < nb_sens) {
        i = blockIdx.x * blockDim.x + threadIdx.x;
        if (i < N_SENS) pred = (0.9f * sens_mem[i] + 5.0f * sens_in[i]) > 1.0f;
        dst = smask; maxw = SENS_MW / 2;
    } else {
        i = (blockIdx.x - nb_sens) * blockDim.x + threadIdx.x;
        if (i < N_HID) pred = (hid_prev[i] != 0.0f);
        dst = hmask; maxw = HID_MW / 2;
    }
    unsigned long long b = __ballot(pred);
    if ((threadIdx.x & 63) == 0) {
        int w = i >> 6;
        if (w < maxw) dst[w] = make_uint2((unsigned)b, (unsigned)(b >> 32));
    }
}

// --- Phase A: two-pass bin (count, reserve, write), LDS mask bit-test ----
__global__ __launch_bounds__(BIN_B, 8)
void bin_edges2(const int* __restrict__ sh_pre, const int* __restrict__ sh_post,
                const float* __restrict__ w_sh, const unsigned* __restrict__ smask,
                int e_sh, int nb_sh,
                const int* __restrict__ hh_pre, const int* __restrict__ hh_post,
                const float* __restrict__ w_hh, const unsigned* __restrict__ hmask,
                int e_hh,
                uint2* __restrict__ pairs, int* __restrict__ cursors) {
    __shared__ unsigned sm[HID_MW];
    __shared__ int h[NBUCKET];
    const int *pre, *post;
    const float* w;
    const unsigned* gm;
    int mw, n_e, blockStart;
    float scale;
    if ((int)blockIdx.x < nb_sh) {
        pre = sh_pre; post = sh_post; w = w_sh; gm = smask;
        mw = SENS_MW; n_e = e_sh; scale = 1.0f;
        blockStart = blockIdx.x * (BIN_B * BIN_EPT);
    } else {
        pre = hh_pre; post = hh_post; w = w_hh; gm = hmask;
        mw = HID_MW; n_e = e_hh; scale = 0.5f;
        blockStart = (blockIdx.x - nb_sh) * (BIN_B * BIN_EPT);
    }
    for (int i = threadIdx.x; i < mw; i += BIN_B) sm[i] = gm[i];
    if (threadIdx.x < NBUCKET) h[threadIdx.x] = 0;
    __syncthreads();

    // pass 1: per-block bucket histogram
    #pragma unroll 4
    for (int j = 0; j < BIN_EPT; ++j) {
        int e = blockStart + j * BIN_B + threadIdx.x;
        if (e < n_e) {
            int pr = pre[e];
            if ((sm[pr >> 5] >> (pr & 31)) & 1u)
                atomicAdd(&h[post[e] >> CHUNK_LOG], 1);
        }
    }
    __syncthreads();
    if (threadIdx.x < NBUCKET)
        h[threadIdx.x] = atomicAdd(&cursors[threadIdx.x], h[threadIdx.x]);
    __syncthreads();

    // pass 2: recompute and write (pre/post re-reads are L2-hot)
    #pragma unroll 4
    for (int j = 0; j < BIN_EPT; ++j) {
        int e = blockStart + j * BIN_B + threadIdx.x;
        if (e < n_e) {
            int pr = pre[e];
            if ((sm[pr >> 5] >> (pr & 31)) & 1u) {
                int p = post[e];
                int b = p >> CHUNK_LOG;
                int slot = atomicAdd(&h[b], 1);
                if (slot < CAP)
                    pairs[(size_t)b * CAP + slot] =
                        make_uint2((unsigned)(p & (CHUNK - 1)),
                                   __float_as_uint(scale * w[e]));
            }
        }
    }
}

// --- Phase B: LDS ds_add accumulation per (bucket, copy) -----------------
__global__ __launch_bounds__(1024, 8)
void accum_bucket(const uint2* __restrict__ pairs,
                  const int* __restrict__ cursors,
                  float* __restrict__ partials) {
    int bucket = blockIdx.x / NCOPY;
    int copy   = blockIdx.x % NCOPY;
    __shared__ float acc[CHUNK];
    for (int i = threadIdx.x; i < CHUNK; i += blockDim.x) acc[i] = 0.0f;
    __syncthreads();

    int count = cursors[bucket];
    if (count > CAP) count = CAP;
    int begin = (int)((long long)count * copy / NCOPY);
    int end   = (int)((long long)count * (copy + 1) / NCOPY);
    const uint2* src = pairs + (size_t)bucket * CAP;
    for (int i = begin + threadIdx.x; i < end; i += blockDim.x) {
        uint2 u = src[i];
        atomicAdd(&acc[u.x], __uint_as_float(u.y));           // LDS atomic
    }
    __syncthreads();
    float* dst = partials + ((size_t)bucket * NCOPY + copy) * CHUNK;
    for (int i = threadIdx.x; i < CHUNK; i += blockDim.x) dst[i] = acc[i];
}

// --- hidden LIF fused with partial merge; emits spike bitmask ------------
__global__ void reduce_lif_hidden_mask(const float* __restrict__ partials,
                                       const float* __restrict__ mem,
                                       uint2* __restrict__ mask) {
    int i = blockIdx.x * blockDim.x + threadIdx.x;
    bool pred = false;
    if (i < N_HID) {
        int b = i >> CHUNK_LOG, local = i & (CHUNK - 1);
        const float* p = partials + (size_t)b * NCOPY * CHUNK + local;
        float sum = 0.0f;
        #pragma unroll
        for (int c = 0; c < NCOPY; ++c) sum += p[(size_t)c * CHUNK];
        pred = (0.9f * mem[i] + 5.0f * sum) > 1.0f;
    }
    unsigned long long bal = __ballot(pred);
    if ((threadIdx.x & 63) == 0) {
        int w = i >> 6;
        if (w < HID_MW / 2)
            mask[w] = make_uint2((unsigned)bal, (unsigned)(bal >> 32));
    }
}

// --- motor: LDS accumulator + LDS hid bitmask, per-block partials --------
__global__ void scatter_motor_mask(const int* __restrict__ pre,
                                   const int* __restrict__ post,
                                   const float* __restrict__ w,
                                   const unsigned* __restrict__ gmask,
                                   float* __restrict__ partials, int n_edges) {
    __shared__ float acc[N_MOT];
    __shared__ unsigned sm[HID_MW];
    for (int i = threadIdx.x; i < HID_MW; i += blockDim.x) sm[i] = gmask[i];
    for (int j = threadIdx.x; j < N_MOT; j += blockDim.x) acc[j] = 0.0f;
    __syncthreads();
    for (int e = blockIdx.x * blockDim.x + threadIdx.x; e < n_edges;
         e += gridDim.x * blockDim.x) {
        int pr = pre[e];
        if ((sm[pr >> 5] >> (pr & 31)) & 1u)
            atomicAdd(&acc[post[e]], w[e]);
    }
    __syncthreads();
    float* out = partials + (size_t)blockIdx.x * N_MOT;
    for (int j = threadIdx.x; j < N_MOT; j += blockDim.x) out[j] = acc[j];
}

__global__ void reduce_lif_motor(const float* __restrict__ partials, int nb,
                                 const float* __restrict__ mem,
                                 float* __restrict__ out) {
    int m = blockIdx.x * blockDim.x + threadIdx.x;
    if (m >= N_MOT) return;
    float sum = 0.0f;
    for (int b = 0; b < nb; ++b) sum += partials[(size_t)b * N_MOT + m];
    float v = 0.9f * mem[m] + 20.0f * sum;
    out[m] = (v > 1.0f) ? 1.0f : 0.0f;
}

// --- fallback (tiny workspace): device-atomic scatter --------------------
__global__ void lif_kernel(const float* __restrict__ inp,
                           const float* __restrict__ mem_in,
                           float* __restrict__ spk,
                           float scale, int n) {
    int i = blockIdx.x * blockDim.x + threadIdx.x;
    if (i < n) {
        float m = 0.9f * mem_in[i] + scale * inp[i];
        spk[i] = (m > 1.0f) ? 1.0f : 0.0f;
    }
}

__global__ void scatter_dev(const int* __restrict__ pre,
                            const int* __restrict__ post,
                            const float* __restrict__ w,
                            const float* __restrict__ spikes,
                            float* __restrict__ out,
                            float scale, int n_edges) {
    int e = blockIdx.x * blockDim.x + threadIdx.x;
    if (e >= n_edges) return;
    float s = spikes[pre[e]];
    if (s != 0.0f) atomicAdd(&out[post[e]], scale * w[e] * s);
}

__global__ void lif_hidden_direct(const float* __restrict__ hid_in,
                                  const float* __restrict__ mem,
                                  float* __restrict__ spk) {
    int i = blockIdx.x * blockDim.x + threadIdx.x;
    if (i >= N_HID) return;
    float m = 0.9f * mem[i] + 5.0f * hid_in[i];
    spk[i] = (m > 1.0f) ? 1.0f : 0.0f;
}

__global__ void scatter_motor_f(const int* __restrict__ pre,
                                const int* __restrict__ post,
                                const float* __restrict__ w,
                                const float* __restrict__ spikes,
                                float* __restrict__ partials, int n_edges) {
    __shared__ float acc[N_MOT];
    for (int j = threadIdx.x; j < N_MOT; j += blockDim.x) acc[j] = 0.0f;
    __syncthreads();
    for (int e = blockIdx.x * blockDim.x + threadIdx.x; e < n_edges;
         e += gridDim.x * blockDim.x) {
        float s = spikes[pre[e]];
        if (s != 0.0f) atomicAdd(&acc[post[e]], w[e] * s);
    }
    __syncthreads();
    float* out = partials + (size_t)blockIdx.x * N_MOT;
    for (int j = threadIdx.x; j < N_MOT; j += blockDim.x) out[j] = acc[j];
}

extern "C" void kernel_launch(void* const* d_in, const int* in_sizes, int n_in,
                              void* d_out, int out_size, void* d_ws, size_t ws_size,
                              hipStream_t stream) {
    const float* sensory_input = (const float*)d_in[0];
    const float* sensory_mem   = (const float*)d_in[1];
    const float* hidden_mem    = (const float*)d_in[2];
    const float* motor_mem     = (const float*)d_in[3];
    const float* hidden_prev   = (const float*)d_in[4];
    const float* w_sh          = (const float*)d_in[5];
    const float* w_hh          = (const float*)d_in[6];
    const float* w_hm          = (const float*)d_in[7];
    const int*   sh_pre        = (const int*)d_in[8];
    const int*   sh_post       = (const int*)d_in[9];
    const int*   hh_pre        = (const int*)d_in[10];
    const int*   hh_post       = (const int*)d_in[11];
    const int*   hm_pre        = (const int*)d_in[12];
    const int*   hm_post       = (const int*)d_in[13];
    const int e_sh = in_sizes[5];
    const int e_hh = in_sizes[6];
    const int e_hm = in_sizes[7];
    const int B = 256;

    // fast ws layout (floats, offsets even -> uint2-aligned):
    size_t o_cursors = 0;                                        // 32
    size_t o_pairs   = 32;                                       // NBUCKET*CAP*2
    size_t o_part    = o_pairs + (size_t)NBUCKET * CAP * 2;      // NBUCKET*NCOPY*CHUNK
    size_t o_smask   = o_part + (size_t)NBUCKET * NCOPY * CHUNK; // SENS_MW
    size_t o_hmaskp  = o_smask + SENS_MW;                        // HID_MW
    size_t o_hmasks  = o_hmaskp + HID_MW;                        // HID_MW
    size_t o_mpart   = o_hmasks + HID_MW;                        // NB_HM*N_MOT
    size_t f_need    = o_mpart + (size_t)NB_HM * N_MOT;
    bool fast = (ws_size / sizeof(float)) >= f_need;

    float* ws = (float*)d_ws;
    if (fast) {
        int*      cursors = (int*)(ws + o_cursors);
        uint2*    pairs   = (uint2*)(ws + o_pairs);
        float*    part    = ws + o_part;
        unsigned* smask   = (unsigned*)(ws + o_smask);
        unsigned* hmaskp  = (unsigned*)(ws + o_hmaskp);
        unsigned* hmasks  = (unsigned*)(ws + o_hmasks);
        float*    mpart   = ws + o_mpart;

        hipMemsetAsync(cursors, 0, 32 * sizeof(int), stream);

        int nb_sens = (N_SENS + B - 1) / B;                      // 40
        int nb_hidm = (N_HID + B - 1) / B;                       // 1563
        make_masks<<<nb_sens + nb_hidm, B, 0, stream>>>(
            sensory_input, sensory_mem, hidden_prev,
            (uint2*)smask, (uint2*)hmaskp, nb_sens);

        int nb_sh = (e_sh + BIN_B * BIN_EPT - 1) / (BIN_B * BIN_EPT);  // 245
        int nb_hh = (e_hh + BIN_B * BIN_EPT - 1) / (BIN_B * BIN_EPT);  // 977
        bin_edges2<<<nb_sh + nb_hh, BIN_B, 0, stream>>>(
            sh_pre, sh_post, w_sh, smask, e_sh, nb_sh,
            hh_pre, hh_post, w_hh, hmaskp, e_hh, pairs, cursors);

        accum_bucket<<<NBUCKET * NCOPY, 1024, 0, stream>>>(pairs, cursors, part);
        reduce_lif_hidden_mask<<<(N_HID + B - 1) / B, B, 0, stream>>>(
            part, hidden_mem, (uint2*)hmasks);
        scatter_motor_mask<<<NB_HM, 512, 0, stream>>>(
            hm_pre, hm_post, w_hm, hmasks, mpart, e_hm);
        reduce_lif_motor<<<(N_MOT + B - 1) / B, B, 0, stream>>>(
            mpart, NB_HM, motor_mem, (float*)d_out);
    } else {
        float* hid_in   = ws;
        float* sens_spk = hid_in + N_HID;
        float* hid_spk  = sens_spk + 10016;
        float* mpart    = hid_spk + N_HID;
        hipMemsetAsync(hid_in, 0, (size_t)N_HID * sizeof(float), stream);
        lif_kernel<<<(N_SENS + B - 1) / B, B, 0, stream>>>(
            sensory_input, sensory_mem, sens_spk, 5.0f, N_SENS);
        scatter_dev<<<(e_sh + B - 1) / B, B, 0, stream>>>(
            sh_pre, sh_post, w_sh, sens_spk, hid_in, 1.0f, e_sh);
        scatter_dev<<<(e_hh + B - 1) / B, B, 0, stream>>>(
            hh_pre, hh_post, w_hh, hidden_prev, hid_in, 0.5f, e_hh);
        lif_hidden_direct<<<(N_HID + B - 1) / B, B, 0, stream>>>(
            hid_in, hidden_mem, hid_spk);
        scatter_motor_f<<<NB_HM, B, 0, stream>>>(
            hm_pre, hm_post, w_hm, hid_spk, mpart, e_hm);
        reduce_lif_motor<<<(N_MOT + B - 1) / B, B, 0, stream>>>(
            mpart, NB_HM, motor_mem, (float*)d_out);
    }
}